// Round 1
// baseline (1212.563 us; speedup 1.0000x reference)
//
#include <hip/hip_runtime.h>
#include <hip/hip_bf16.h>

// Shapes
#define BB 512
#define CC 63
#define TT 250
#define SS 10
#define O1 40
#define WP 46      // pooled width
#define K2 2520    // 40*63
#define EE 4
#define HID 184
#define PROJ 1024
#define N1F (512.f*63.f*46.f)
#define N2F (512.f*46.f)

// ---------------- Kernel Z: zero the bn1 atomic accumulators ----------------
__global__ void kZ(float* stats) {
    int t = threadIdx.x;
    if (t < 80) stats[t] = 0.f;
}

// ---------------- Kernel A: x_eeg[b,c,s] = sum_t x[b,c,t]*W[subj,s,t] + bg[subj,s]
// grid (8 s-tiles, 512 b), block 256. Tile: 64 rows(c) x 32 cols(s), K-chunk 32.
__global__ __launch_bounds__(256) void kA(const float* __restrict__ x,
                                          const int* __restrict__ subj,
                                          const float* __restrict__ Wsub,
                                          const float* __restrict__ bsub,
                                          float* __restrict__ xeeg) {
    int s0 = blockIdx.x * 32;
    int b  = blockIdx.y;
    int sj = subj[b];
    const float* Wb = Wsub + (size_t)sj * 250 * 250;
    __shared__ float xs[64 * 36];
    __shared__ float wsh[32 * 36];
    int tid = threadIdx.x;
    int tx = tid & 7, ty = tid >> 3;          // tx: s-group (4 each), ty: 0..31 (rows ty, ty+32)
    float acc[2][4] = {{0.f,0.f,0.f,0.f},{0.f,0.f,0.f,0.f}};

    for (int t0 = 0; t0 < 250; t0 += 32) {
        for (int i = tid; i < 2048; i += 256) {
            int k = i & 31, c = i >> 5;
            int t = t0 + k;
            xs[c*36 + k] = (c < 63 && t < 250) ? x[((size_t)b*63 + c)*250 + t] : 0.f;
        }
        for (int i = tid; i < 1024; i += 256) {
            int k = i & 31, sr = i >> 5;
            int s = s0 + sr, t = t0 + k;
            wsh[sr*36 + k] = (s < 250 && t < 250) ? Wb[(size_t)s*250 + t] : 0.f;
        }
        __syncthreads();
        #pragma unroll
        for (int k4 = 0; k4 < 32; k4 += 4) {
            float4 xa = *(const float4*)&xs[ty*36 + k4];
            float4 xb = *(const float4*)&xs[(ty+32)*36 + k4];
            #pragma unroll
            for (int q = 0; q < 4; ++q) {
                float4 w4 = *(const float4*)&wsh[(tx + 8*q)*36 + k4];
                acc[0][q] += xa.x*w4.x + xa.y*w4.y + xa.z*w4.z + xa.w*w4.w;
                acc[1][q] += xb.x*w4.x + xb.y*w4.y + xb.z*w4.z + xb.w*w4.w;
            }
        }
        __syncthreads();
    }
    #pragma unroll
    for (int q = 0; q < 4; ++q) {
        int s = s0 + tx + 8*q;
        if (s < 250) {
            float bgv = bsub[sj*250 + s];
            int c0 = ty;
            xeeg[((size_t)b*63 + c0)*250 + s] = acc[0][q] + bgv;
            int c1 = ty + 32;
            if (c1 < 63) xeeg[((size_t)b*63 + c1)*250 + s] = acc[1][q] + bgv;
        }
    }
}

// ---------------- Kernel B: fused conv1(1x5)+avgpool(17,s5) -> pooled bf16 [b][w][o][c]
// plus bn1 partial sums (atomics). grid (512 b, 3 c-tiles of 21), block 256.
__global__ __launch_bounds__(256) void kB(const float* __restrict__ xeeg,
                                          const float* __restrict__ w1,
                                          const float* __restrict__ b1,
                                          __hip_bfloat16* __restrict__ pooled,
                                          float* __restrict__ stats) {
    int b = blockIdx.x, ct = blockIdx.y;
    int c0 = ct * 21;
    __shared__ float xs[21 * 251];
    __shared__ float effs[40 * 21];
    __shared__ float psum[4][40], psq[4][40];
    int tid = threadIdx.x;

    for (int i = tid; i < 21 * 250; i += 256) {
        int c = i / 250, t = i - c * 250;
        xs[c*251 + t] = xeeg[((size_t)b*63 + c0 + c)*250 + t];
    }
    for (int i = tid; i < 840; i += 256) {
        int o = i / 21, j = i - o * 21;
        float e = 0.f;
        #pragma unroll
        for (int k = 0; k < 5; ++k) { int u = j - k; if (u >= 0 && u <= 16) e += w1[o*5 + k]; }
        effs[i] = e * (1.f / 17.f);
    }
    __syncthreads();

    int wave = tid >> 6, lane = tid & 63;
    for (int o = 0; o < 40; ++o) {
        float eff[21];
        #pragma unroll
        for (int j = 0; j < 21; ++j) eff[j] = effs[o*21 + j];
        float bo = b1[o];
        float ssum = 0.f, ssq = 0.f;
        for (int e = tid; e < 966; e += 256) {   // 21*46
            int c = e % 21, w = e / 21;
            float acc = bo;
            #pragma unroll
            for (int j = 0; j < 21; ++j) acc += xs[c*251 + 5*w + j] * eff[j];
            pooled[(((size_t)b*46 + w)*40 + o)*63 + c0 + c] = __float2bfloat16(acc);
            ssum += acc; ssq += acc*acc;
        }
        #pragma unroll
        for (int d = 32; d >= 1; d >>= 1) { ssum += __shfl_down(ssum, d); ssq += __shfl_down(ssq, d); }
        if (lane == 0) { psum[wave][o] = ssum; psq[wave][o] = ssq; }
    }
    __syncthreads();
    if (tid < 40) {
        float s = psum[0][tid] + psum[1][tid] + psum[2][tid] + psum[3][tid];
        float q = psq[0][tid] + psq[1][tid] + psq[2][tid] + psq[3][tid];
        atomicAdd(&stats[tid], s);
        atomicAdd(&stats[40 + tid], q);
    }
}

// ---------------- Kernel C: finalize bn1 -> scale1/shift1
__global__ void kC(float* stats, const float* __restrict__ g1, const float* __restrict__ bb1) {
    int t = threadIdx.x;
    if (t < 40) {
        float mean = stats[t] / N1F;
        float var  = stats[40 + t] / N1F - mean * mean;
        float sc   = g1[t] * rsqrtf(var + 1e-5f);
        stats[80 + t]  = sc;
        stats[120 + t] = bb1[t] - mean * sc;
    }
}

// ---------------- Kernel D: conv2 as GEMM: out2[m,n] = sum_k elu(bn1(pooled[m,k]))*w2[n,k] + b2[n]
// M = 23552 (b*46+w), N = 40, K = 2520. grid 368 (M-tiles of 64), block 256.
__global__ __launch_bounds__(256) void kD(const __hip_bfloat16* __restrict__ pooled,
                                          const float* __restrict__ w2,
                                          const float* __restrict__ b2,
                                          const float* __restrict__ stats,
                                          float* __restrict__ out2) {
    int m0 = blockIdx.x * 64;
    __shared__ float As[64 * 36];
    __shared__ float Ws[40 * 36];
    __shared__ float sc1[40], sh1[40];
    int tid = threadIdx.x;
    if (tid < 40) { sc1[tid] = stats[80 + tid]; sh1[tid] = stats[120 + tid]; }
    __syncthreads();
    int tx = tid & 7, ty = tid >> 3;
    float acc[2][5] = {{0,0,0,0,0},{0,0,0,0,0}};

    for (int k0 = 0; k0 < K2; k0 += 32) {
        for (int i = tid; i < 2048; i += 256) {
            int k = i & 31, r = i >> 5;
            int kk = k0 + k;
            float v = 0.f;
            if (kk < K2) {
                int o = kk / 63;
                float p = __bfloat162float(pooled[(size_t)(m0 + r)*K2 + kk]);
                float a = p * sc1[o] + sh1[o];
                v = a > 0.f ? a : expf(a) - 1.f;
            }
            As[r*36 + k] = v;
        }
        for (int i = tid; i < 1280; i += 256) {
            int k = i & 31, n = i >> 5;
            int kk = k0 + k;
            Ws[n*36 + k] = (kk < K2) ? w2[(size_t)n*K2 + kk] : 0.f;
        }
        __syncthreads();
        #pragma unroll
        for (int k4 = 0; k4 < 32; k4 += 4) {
            float4 a0 = *(const float4*)&As[ty*36 + k4];
            float4 a1 = *(const float4*)&As[(ty+32)*36 + k4];
            #pragma unroll
            for (int q = 0; q < 5; ++q) {
                float4 w4 = *(const float4*)&Ws[(tx + 8*q)*36 + k4];
                acc[0][q] += a0.x*w4.x + a0.y*w4.y + a0.z*w4.z + a0.w*w4.w;
                acc[1][q] += a1.x*w4.x + a1.y*w4.y + a1.z*w4.z + a1.w*w4.w;
            }
        }
        __syncthreads();
    }
    #pragma unroll
    for (int q = 0; q < 5; ++q) {
        int n = tx + 8*q;
        float bb = b2[n];
        out2[(size_t)(m0 + ty)*40 + n]      = acc[0][q] + bb;
        out2[(size_t)(m0 + ty + 32)*40 + n] = acc[1][q] + bb;
    }
}

// ---------------- Kernel E: bn2 stats + finalize. grid 40 (one block per channel).
__global__ __launch_bounds__(256) void kE(const float* __restrict__ out2, float* stats,
                                          const float* __restrict__ g2, const float* __restrict__ bb2) {
    int o = blockIdx.x, tid = threadIdx.x;
    float s = 0.f, q = 0.f;
    for (int m = tid; m < 23552; m += 256) {
        float v = out2[(size_t)m*40 + o];
        s += v; q += v*v;
    }
    __shared__ float ps[4], pq[4];
    int wave = tid >> 6, lane = tid & 63;
    #pragma unroll
    for (int d = 32; d >= 1; d >>= 1) { s += __shfl_down(s, d); q += __shfl_down(q, d); }
    if (lane == 0) { ps[wave] = s; pq[wave] = q; }
    __syncthreads();
    if (tid == 0) {
        float S = ps[0]+ps[1]+ps[2]+ps[3], Q = pq[0]+pq[1]+pq[2]+pq[3];
        float mean = S / N2F, var = Q / N2F - mean*mean;
        float sc = g2[o] * rsqrtf(var + 1e-5f);
        stats[160 + o] = sc;
        stats[200 + o] = bb2[o] - mean * sc;
    }
}

// ---------------- Kernel F: bn2+elu+proj -> z[b, w*4+e]. grid 512.
__global__ void kF(const float* __restrict__ out2, const float* __restrict__ stats,
                   const float* __restrict__ pw, const float* __restrict__ pb,
                   float* __restrict__ z) {
    int b = blockIdx.x, t = threadIdx.x;
    __shared__ float sc[40], sh[40], pws[160];
    if (t < 40) { sc[t] = stats[160 + t]; sh[t] = stats[200 + t]; }
    if (t < 160) pws[t] = pw[t];
    __syncthreads();
    if (t < 184) {
        int w = t >> 2, e = t & 3;
        float acc = pb[e];
        for (int o = 0; o < 40; ++o) {
            float a = out2[((size_t)b*46 + w)*40 + o];
            float act = a * sc[o] + sh[o];
            act = act > 0.f ? act : expf(act) - 1.f;
            acc += act * pws[e*40 + o];
        }
        z[(size_t)b*184 + t] = acc;
    }
}

// ---------------- Kernel G1: h1 = z @ fc1_w^T + b; g = gelu(h1). M=512,N=1024,K=184.
__global__ __launch_bounds__(256) void kG1(const float* __restrict__ z, const float* __restrict__ fw,
                                           const float* __restrict__ fb,
                                           float* __restrict__ h1, float* __restrict__ g) {
    int n0 = blockIdx.x * 64, m0 = blockIdx.y * 64;
    __shared__ float As[64 * 36], Bs[64 * 36];
    int tid = threadIdx.x;
    int tx = tid & 15, ty = tid >> 4;
    float acc[4][4] = {};
    for (int k0 = 0; k0 < HID; k0 += 32) {
        for (int i = tid; i < 2048; i += 256) {
            int k = i & 31, r = i >> 5;
            int kk = k0 + k;
            As[r*36 + k] = (kk < HID) ? z[(size_t)(m0 + r)*HID + kk] : 0.f;
            Bs[r*36 + k] = (kk < HID) ? fw[(size_t)(n0 + r)*HID + kk] : 0.f;
        }
        __syncthreads();
        #pragma unroll
        for (int k4 = 0; k4 < 32; k4 += 4) {
            float4 a[4], bv[4];
            #pragma unroll
            for (int r = 0; r < 4; ++r) a[r] = *(const float4*)&As[(ty + 16*r)*36 + k4];
            #pragma unroll
            for (int q = 0; q < 4; ++q) bv[q] = *(const float4*)&Bs[(tx + 16*q)*36 + k4];
            #pragma unroll
            for (int r = 0; r < 4; ++r)
                #pragma unroll
                for (int q = 0; q < 4; ++q)
                    acc[r][q] += a[r].x*bv[q].x + a[r].y*bv[q].y + a[r].z*bv[q].z + a[r].w*bv[q].w;
        }
        __syncthreads();
    }
    #pragma unroll
    for (int r = 0; r < 4; ++r) {
        int m = m0 + ty + 16*r;
        #pragma unroll
        for (int q = 0; q < 4; ++q) {
            int n = n0 + tx + 16*q;
            float v = acc[r][q] + fb[n];
            h1[(size_t)m*PROJ + n] = v;
            g[(size_t)m*PROJ + n] = 0.5f * v * (1.f + erff(v * 0.70710678118f));
        }
    }
}

// ---------------- Kernel G2: h2 = h1 + (g @ fc2_w^T + b2). M=512,N=1024,K=1024.
__global__ __launch_bounds__(256) void kG2(const float* __restrict__ g, const float* __restrict__ fw,
                                           const float* __restrict__ fb, const float* __restrict__ h1,
                                           float* __restrict__ h2) {
    int n0 = blockIdx.x * 64, m0 = blockIdx.y * 64;
    __shared__ float As[64 * 36], Bs[64 * 36];
    int tid = threadIdx.x;
    int tx = tid & 15, ty = tid >> 4;
    float acc[4][4] = {};
    for (int k0 = 0; k0 < PROJ; k0 += 32) {
        for (int i = tid; i < 2048; i += 256) {
            int k = i & 31, r = i >> 5;
            int kk = k0 + k;
            As[r*36 + k] = g[(size_t)(m0 + r)*PROJ + kk];
            Bs[r*36 + k] = fw[(size_t)(n0 + r)*PROJ + kk];
        }
        __syncthreads();
        #pragma unroll
        for (int k4 = 0; k4 < 32; k4 += 4) {
            float4 a[4], bv[4];
            #pragma unroll
            for (int r = 0; r < 4; ++r) a[r] = *(const float4*)&As[(ty + 16*r)*36 + k4];
            #pragma unroll
            for (int q = 0; q < 4; ++q) bv[q] = *(const float4*)&Bs[(tx + 16*q)*36 + k4];
            #pragma unroll
            for (int r = 0; r < 4; ++r)
                #pragma unroll
                for (int q = 0; q < 4; ++q)
                    acc[r][q] += a[r].x*bv[q].x + a[r].y*bv[q].y + a[r].z*bv[q].z + a[r].w*bv[q].w;
        }
        __syncthreads();
    }
    #pragma unroll
    for (int r = 0; r < 4; ++r) {
        int m = m0 + ty + 16*r;
        #pragma unroll
        for (int q = 0; q < 4; ++q) {
            int n = n0 + tx + 16*q;
            h2[(size_t)m*PROJ + n] = acc[r][q] + fb[n] + h1[(size_t)m*PROJ + n];
        }
    }
}

// ---------------- Kernel G3: LayerNorm rows of 1024 -> out. grid 512.
__global__ __launch_bounds__(256) void kG3(const float* __restrict__ h2, const float* __restrict__ lg,
                                           const float* __restrict__ lb, float* __restrict__ out) {
    int b = blockIdx.x, tid = threadIdx.x;
    float4 v = *(const float4*)&h2[(size_t)b*PROJ + tid*4];
    float s = v.x + v.y + v.z + v.w;
    float q = v.x*v.x + v.y*v.y + v.z*v.z + v.w*v.w;
    __shared__ float ps[4], pq[4], mb[2];
    int wave = tid >> 6, lane = tid & 63;
    #pragma unroll
    for (int d = 32; d >= 1; d >>= 1) { s += __shfl_down(s, d); q += __shfl_down(q, d); }
    if (lane == 0) { ps[wave] = s; pq[wave] = q; }
    __syncthreads();
    if (tid == 0) {
        float S = ps[0]+ps[1]+ps[2]+ps[3], Q = pq[0]+pq[1]+pq[2]+pq[3];
        float mean = S / 1024.f, var = Q / 1024.f - mean*mean;
        mb[0] = mean; mb[1] = rsqrtf(var + 1e-5f);
    }
    __syncthreads();
    float mean = mb[0], inv = mb[1];
    float4 g4 = *(const float4*)&lg[tid*4];
    float4 b4 = *(const float4*)&lb[tid*4];
    float4 o4;
    o4.x = (v.x - mean)*inv*g4.x + b4.x;
    o4.y = (v.y - mean)*inv*g4.y + b4.y;
    o4.z = (v.z - mean)*inv*g4.z + b4.z;
    o4.w = (v.w - mean)*inv*g4.w + b4.w;
    *(float4*)&out[(size_t)b*PROJ + tid*4] = o4;
}

extern "C" void kernel_launch(void* const* d_in, const int* in_sizes, int n_in,
                              void* d_out, int out_size, void* d_ws, size_t ws_size,
                              hipStream_t stream) {
    const float* x       = (const float*)d_in[0];
    const int*   subjects= (const int*)  d_in[1];
    const float* W_subj  = (const float*)d_in[2];
    const float* b_subj  = (const float*)d_in[3];
    const float* conv1_w = (const float*)d_in[4];
    const float* conv1_b = (const float*)d_in[5];
    const float* bn1_g   = (const float*)d_in[6];
    const float* bn1_b   = (const float*)d_in[7];
    const float* conv2_w = (const float*)d_in[8];
    const float* conv2_b = (const float*)d_in[9];
    const float* bn2_g   = (const float*)d_in[10];
    const float* bn2_b   = (const float*)d_in[11];
    const float* proj_w  = (const float*)d_in[12];
    const float* proj_b  = (const float*)d_in[13];
    const float* fc1_w   = (const float*)d_in[14];
    const float* fc1_b   = (const float*)d_in[15];
    const float* fc2_w   = (const float*)d_in[16];
    const float* fc2_b   = (const float*)d_in[17];
    const float* ln_g    = (const float*)d_in[18];
    const float* ln_b    = (const float*)d_in[19];
    float* out = (float*)d_out;

    char* ws = (char*)d_ws;
    float* xeeg = (float*)ws;                                        // 8,064,000 f32
    __hip_bfloat16* pooled = (__hip_bfloat16*)(ws + 32256000);       // 59,351,040 bf16
    float* out2 = (float*)(ws + 32256000 + 118702080);               // 942,080 f32
    float* z    = out2 + 942080;                                     // 94,208
    float* h1   = z + 94208;                                         // 524,288
    float* g    = h1 + 524288;                                       // 524,288
    float* h2   = g + 524288;                                        // 524,288
    float* stats= h2 + 524288;                                       // 256

    kZ <<<1, 128, 0, stream>>>(stats);
    kA <<<dim3(8, 512), 256, 0, stream>>>(x, subjects, W_subj, b_subj, xeeg);
    kB <<<dim3(512, 3), 256, 0, stream>>>(xeeg, conv1_w, conv1_b, pooled, stats);
    kC <<<1, 64, 0, stream>>>(stats, bn1_g, bn1_b);
    kD <<<368, 256, 0, stream>>>(pooled, conv2_w, conv2_b, stats, out2);
    kE <<<40, 256, 0, stream>>>(out2, stats, bn2_g, bn2_b);
    kF <<<512, 256, 0, stream>>>(out2, stats, proj_w, proj_b, z);
    kG1<<<dim3(16, 8), 256, 0, stream>>>(z, fc1_w, fc1_b, h1, g);
    kG2<<<dim3(16, 8), 256, 0, stream>>>(g, fc2_w, fc2_b, h1, h2);
    kG3<<<512, 256, 0, stream>>>(h2, ln_g, ln_b, out);
    (void)in_sizes; (void)n_in; (void)out_size; (void)ws_size;
}

// Round 2
// 483.368 us; speedup vs baseline: 2.5086x; 2.5086x over previous
//
#include <hip/hip_runtime.h>
#include <hip/hip_bf16.h>

#define K2 2520
#define PROJ 1024
#define HID 184
#define N1F (512.f*63.f*46.f)
#define N2F (512.f*46.f)

typedef float f32x4 __attribute__((ext_vector_type(4)));
typedef short bf16x8 __attribute__((ext_vector_type(8)));
typedef unsigned short u16;
typedef unsigned short ushort8 __attribute__((ext_vector_type(8)));

__device__ __forceinline__ u16 f2bf(float f) {   // RNE fp32 -> bf16 bits
    unsigned u = __builtin_bit_cast(unsigned, f);
    return (u16)((u + 0x7FFFu + ((u >> 16) & 1u)) >> 16);
}
__device__ __forceinline__ float bf2f(u16 h) {
    unsigned u = ((unsigned)h) << 16;
    return __builtin_bit_cast(float, u);
}

// ---------------- kZ: zero stats[0..320) ----------------
__global__ void kZ(float* stats) {
    int t = threadIdx.x;
    if (t < 320) stats[t] = 0.f;
}

// ---------------- prep: W_subj -> bf16 [10][256][256], zero-padded ----------------
__global__ void kXa(const float* __restrict__ W, u16* __restrict__ Wbf) {
    int i = blockIdx.x * 256 + threadIdx.x;          // grid 2560
    int sj = i >> 16, s_ = (i >> 8) & 255, t_ = i & 255;
    float v = (s_ < 250 && t_ < 250) ? W[(size_t)sj*62500 + s_*250 + t_] : 0.f;
    Wbf[i] = f2bf(v);
}
// ---------------- prep: conv2_w -> bf16 [48][2528], zero-padded ----------------
__global__ void kXd(const float* __restrict__ w2, u16* __restrict__ Wbf2) {
    int i = blockIdx.x * 256 + threadIdx.x;          // grid 474 (=121344/256)
    int n = i / 2528, k = i - n * 2528;
    float v = (n < 40 && k < K2) ? w2[n*K2 + k] : 0.f;
    Wbf2[i] = f2bf(v);
}
// ---------------- prep: fc2_w -> bf16 [1024][1024] ----------------
__global__ void kXg(const float* __restrict__ fw, u16* __restrict__ fwbf) {
    int i = blockIdx.x * 256 + threadIdx.x;          // grid 4096
    fwbf[i] = f2bf(fw[i]);
}

// ---------------- kA: x_eeg[b,c,s] = sum_t x[b,c,t]*W[sj][s,t] + bg  (MFMA) ----------------
// grid 512 (b), block 256 (4 waves x 16 rows). N=250 in 16 frags, K=250 in 8 steps.
__global__ __launch_bounds__(256) void kA(const float* __restrict__ x,
                                          const int* __restrict__ subj,
                                          const u16* __restrict__ Wbf,
                                          const float* __restrict__ bsub,
                                          float* __restrict__ xeeg) {
    int b = blockIdx.x;
    int sj = subj[b];
    int tid = threadIdx.x;
    int wv = tid >> 6, lane = tid & 63;
    int row = lane & 15, kg = lane >> 4;
    int c = wv*16 + row;
    const float* xr = x + ((size_t)b*63 + (c < 63 ? c : 0))*250;
    const u16* Wb = Wbf + (size_t)sj*65536;
    f32x4 acc[16];
    #pragma unroll
    for (int i = 0; i < 16; ++i) acc[i] = (f32x4){0.f,0.f,0.f,0.f};

    #pragma unroll
    for (int ks = 0; ks < 8; ++ks) {
        int tb = ks*32 + kg*8;
        float av[8];
        if (ks < 7) {
            #pragma unroll
            for (int j = 0; j < 8; j += 2) { float2 v = *(const float2*)&xr[tb+j]; av[j]=v.x; av[j+1]=v.y; }
        } else {
            #pragma unroll
            for (int j = 0; j < 8; ++j) av[j] = 0.f;
            if (kg < 3) {
                #pragma unroll
                for (int j = 0; j < 8; j += 2) { float2 v = *(const float2*)&xr[tb+j]; av[j]=v.x; av[j+1]=v.y; }
            } else {
                float2 v = *(const float2*)&xr[248]; av[0]=v.x; av[1]=v.y;
            }
        }
        bf16x8 af;
        #pragma unroll
        for (int j = 0; j < 8; ++j) af[j] = (short)f2bf(av[j]);
        #pragma unroll
        for (int nf = 0; nf < 16; ++nf) {
            bf16x8 bv = *(const bf16x8*)(Wb + (size_t)(nf*16 + row)*256 + tb);
            acc[nf] = __builtin_amdgcn_mfma_f32_16x16x32_bf16(af, bv, acc[nf], 0, 0, 0);
        }
    }
    int cD = wv*16 + kg*4;
    #pragma unroll
    for (int nf = 0; nf < 16; ++nf) {
        int s = nf*16 + row;
        if (s < 250) {
            float bias = bsub[sj*250 + s];
            #pragma unroll
            for (int r = 0; r < 4; ++r) {
                int c2 = cD + r;
                if (c2 < 63) xeeg[((size_t)b*63 + c2)*250 + s] = acc[nf][r] + bias;
            }
        }
    }
}

// ---------------- kB: fused conv1(1x5)+avgpool(17,5) -> pooled bf16 [b][w][o][c], bn1 sums ----
__global__ __launch_bounds__(256) void kB(const float* __restrict__ xeeg,
                                          const float* __restrict__ w1,
                                          const float* __restrict__ b1,
                                          __hip_bfloat16* __restrict__ pooled,
                                          float* __restrict__ stats) {
    int b = blockIdx.x, ct = blockIdx.y;
    int c0 = ct * 21;
    __shared__ float xs[21 * 251];
    __shared__ float effs[40 * 21];
    __shared__ float psum[4][40], psq[4][40];
    int tid = threadIdx.x;

    for (int i = tid; i < 21 * 250; i += 256) {
        int c = i / 250, t = i - c * 250;
        xs[c*251 + t] = xeeg[((size_t)b*63 + c0 + c)*250 + t];
    }
    for (int i = tid; i < 840; i += 256) {
        int o = i / 21, j = i - o * 21;
        float e = 0.f;
        #pragma unroll
        for (int k = 0; k < 5; ++k) { int u = j - k; if (u >= 0 && u <= 16) e += w1[o*5 + k]; }
        effs[i] = e * (1.f / 17.f);
    }
    __syncthreads();

    int wave = tid >> 6, lane = tid & 63;
    for (int o = 0; o < 40; ++o) {
        float eff[21];
        #pragma unroll
        for (int j = 0; j < 21; ++j) eff[j] = effs[o*21 + j];
        float bo = b1[o];
        float ssum = 0.f, ssq = 0.f;
        for (int e = tid; e < 966; e += 256) {
            int c = e % 21, w = e / 21;
            float acc = bo;
            #pragma unroll
            for (int j = 0; j < 21; ++j) acc += xs[c*251 + 5*w + j] * eff[j];
            pooled[(((size_t)b*46 + w)*40 + o)*63 + c0 + c] = __float2bfloat16(acc);
            ssum += acc; ssq += acc*acc;
        }
        #pragma unroll
        for (int d = 32; d >= 1; d >>= 1) { ssum += __shfl_down(ssum, d); ssq += __shfl_down(ssq, d); }
        if (lane == 0) { psum[wave][o] = ssum; psq[wave][o] = ssq; }
    }
    __syncthreads();
    if (tid < 40) {
        float s = psum[0][tid] + psum[1][tid] + psum[2][tid] + psum[3][tid];
        float q = psq[0][tid] + psq[1][tid] + psq[2][tid] + psq[3][tid];
        atomicAdd(&stats[tid], s);
        atomicAdd(&stats[40 + tid], q);
    }
}

// ---------------- kC: finalize bn1 -> sc1/sh1 ----------------
__global__ void kC(float* stats, const float* __restrict__ g1, const float* __restrict__ bb1) {
    int t = threadIdx.x;
    if (t < 40) {
        float mean = stats[t] / N1F;
        float var  = stats[40 + t] / N1F - mean * mean;
        float sc   = g1[t] * rsqrtf(var + 1e-5f);
        stats[80 + t]  = sc;
        stats[120 + t] = bb1[t] - mean * sc;
    }
}

// ---------------- kD: out2 = elu(bn1(pooled)) @ w2^T + b2  (MFMA) + bn2 partial sums -------
// M=23552 (368x64), N=40 (3 frags of 16, padded), K=2520 (79 steps, kg-guarded tail).
__global__ __launch_bounds__(256) void kD(const u16* __restrict__ pooled,
                                          const u16* __restrict__ Wbf2,
                                          const float* __restrict__ b2,
                                          const float* __restrict__ stats,
                                          float* __restrict__ out2,
                                          float* __restrict__ statw) {
    __shared__ float sc[40], sh[40];
    __shared__ float redS[4][48], redQ[4][48];
    int tid = threadIdx.x;
    if (tid < 40) { sc[tid] = stats[80 + tid]; sh[tid] = stats[120 + tid]; }
    __syncthreads();
    int wv = tid >> 6, lane = tid & 63, row = lane & 15, kg = lane >> 4;
    int mbase = blockIdx.x*64 + wv*16;
    const u16* pr = pooled + (size_t)(mbase + row) * K2;
    f32x4 acc[3];
    #pragma unroll
    for (int i = 0; i < 3; ++i) acc[i] = (f32x4){0.f,0.f,0.f,0.f};

    ushort8 raw = *(const ushort8*)&pr[kg*8];
    for (int ks = 0; ks < 79; ++ks) {
        int kbase = ks*32 + kg*8;
        ushort8 cur = raw;
        if (ks < 78) raw = *(const ushort8*)&pr[(ks+1)*32 + kg*8];
        bf16x8 bv0 = *(const bf16x8*)(Wbf2 + (size_t)(row     )*2528 + kbase);
        bf16x8 bv1 = *(const bf16x8*)(Wbf2 + (size_t)(16 + row)*2528 + kbase);
        bf16x8 bv2 = *(const bf16x8*)(Wbf2 + (size_t)(32 + row)*2528 + kbase);
        bf16x8 af;
        bool valid = (ks < 78) | (kg < 3);
        if (valid) {
            #pragma unroll
            for (int j = 0; j < 8; ++j) {
                int k = kbase + j;
                float f = bf2f(cur[j]);
                int o = (k * 16645) >> 20;           // k/63 for k<2520
                float a = fmaf(f, sc[o], sh[o]);
                float e = a > 0.f ? a : __expf(a) - 1.f;
                af[j] = (short)f2bf(e);
            }
        } else {
            #pragma unroll
            for (int j = 0; j < 8; ++j) af[j] = 0;
        }
        acc[0] = __builtin_amdgcn_mfma_f32_16x16x32_bf16(af, bv0, acc[0], 0, 0, 0);
        acc[1] = __builtin_amdgcn_mfma_f32_16x16x32_bf16(af, bv1, acc[1], 0, 0, 0);
        acc[2] = __builtin_amdgcn_mfma_f32_16x16x32_bf16(af, bv2, acc[2], 0, 0, 0);
    }

    // store + bn2 partial sums
    float sN[3] = {0.f,0.f,0.f}, qN[3] = {0.f,0.f,0.f};
    #pragma unroll
    for (int nf = 0; nf < 3; ++nf) {
        int n = nf*16 + row;
        if (n < 40) {
            float bias = b2[n];
            #pragma unroll
            for (int r = 0; r < 4; ++r) {
                float v = acc[nf][r] + bias;
                out2[(size_t)(mbase + kg*4 + r)*40 + n] = v;
                sN[nf] += v; qN[nf] += v*v;
            }
        }
    }
    #pragma unroll
    for (int nf = 0; nf < 3; ++nf) {
        float s = sN[nf], q = qN[nf];
        s += __shfl_xor(s, 16); q += __shfl_xor(q, 16);
        s += __shfl_xor(s, 32); q += __shfl_xor(q, 32);
        if (kg == 0) { redS[wv][nf*16 + row] = s; redQ[wv][nf*16 + row] = q; }
    }
    __syncthreads();
    if (tid < 40) {
        float S = redS[0][tid] + redS[1][tid] + redS[2][tid] + redS[3][tid];
        float Q = redQ[0][tid] + redQ[1][tid] + redQ[2][tid] + redQ[3][tid];
        atomicAdd(&statw[160 + tid], S);
        atomicAdd(&statw[200 + tid], Q);
    }
}

// ---------------- kE2: finalize bn2 -> sc2/sh2 ----------------
__global__ void kE2(float* stats, const float* __restrict__ g2, const float* __restrict__ bb2) {
    int t = threadIdx.x;
    if (t < 40) {
        float mean = stats[160 + t] / N2F;
        float var  = stats[200 + t] / N2F - mean * mean;
        float s    = g2[t] * rsqrtf(var + 1e-5f);
        stats[240 + t] = s;
        stats[280 + t] = bb2[t] - mean * s;
    }
}

// ---------------- kF: bn2+elu+proj -> z[b, w*4+e] ----------------
__global__ void kF(const float* __restrict__ out2, const float* __restrict__ stats,
                   const float* __restrict__ pw, const float* __restrict__ pb,
                   float* __restrict__ z) {
    int b = blockIdx.x, t = threadIdx.x;
    __shared__ float sc[40], sh[40], pws[160];
    if (t < 40) { sc[t] = stats[240 + t]; sh[t] = stats[280 + t]; }
    if (t < 160) pws[t] = pw[t];
    __syncthreads();
    if (t < 184) {
        int w = t >> 2, e = t & 3;
        float acc = pb[e];
        for (int o = 0; o < 40; ++o) {
            float a = out2[((size_t)b*46 + w)*40 + o];
            float act = a * sc[o] + sh[o];
            act = act > 0.f ? act : __expf(act) - 1.f;
            acc += act * pws[e*40 + o];
        }
        z[(size_t)b*184 + t] = acc;
    }
}

// ---------------- kG1: h1 = z @ fc1_w^T + b (fp32); g = gelu(h1) as bf16 ----------------
__global__ __launch_bounds__(256) void kG1(const float* __restrict__ z, const float* __restrict__ fw,
                                           const float* __restrict__ fb,
                                           float* __restrict__ h1, u16* __restrict__ gbf) {
    int n0 = blockIdx.x * 64, m0 = blockIdx.y * 64;
    __shared__ float As[64 * 36], Bs[64 * 36];
    int tid = threadIdx.x;
    int tx = tid & 15, ty = tid >> 4;
    float acc[4][4] = {};
    for (int k0 = 0; k0 < HID; k0 += 32) {
        for (int i = tid; i < 2048; i += 256) {
            int k = i & 31, r = i >> 5;
            int kk = k0 + k;
            As[r*36 + k] = (kk < HID) ? z[(size_t)(m0 + r)*HID + kk] : 0.f;
            Bs[r*36 + k] = (kk < HID) ? fw[(size_t)(n0 + r)*HID + kk] : 0.f;
        }
        __syncthreads();
        #pragma unroll
        for (int k4 = 0; k4 < 32; k4 += 4) {
            float4 a[4], bv[4];
            #pragma unroll
            for (int r = 0; r < 4; ++r) a[r] = *(const float4*)&As[(ty + 16*r)*36 + k4];
            #pragma unroll
            for (int q = 0; q < 4; ++q) bv[q] = *(const float4*)&Bs[(tx + 16*q)*36 + k4];
            #pragma unroll
            for (int r = 0; r < 4; ++r)
                #pragma unroll
                for (int q = 0; q < 4; ++q)
                    acc[r][q] += a[r].x*bv[q].x + a[r].y*bv[q].y + a[r].z*bv[q].z + a[r].w*bv[q].w;
        }
        __syncthreads();
    }
    #pragma unroll
    for (int r = 0; r < 4; ++r) {
        int m = m0 + ty + 16*r;
        #pragma unroll
        for (int q = 0; q < 4; ++q) {
            int n = n0 + tx + 16*q;
            float v = acc[r][q] + fb[n];
            h1[(size_t)m*PROJ + n] = v;
            float ge = 0.5f * v * (1.f + erff(v * 0.70710678118f));
            gbf[(size_t)m*PROJ + n] = f2bf(ge);
        }
    }
}

// ---------------- kG2: h2 = h1 + g @ fc2_w^T + b  (MFMA bf16) ----------------
// grid (32 n-tiles of 32, 8 m-tiles of 64), block 256.
__global__ __launch_bounds__(256) void kG2(const u16* __restrict__ gbf, const u16* __restrict__ fwbf,
                                           const float* __restrict__ fb, const float* __restrict__ h1,
                                           float* __restrict__ h2) {
    int n0 = blockIdx.x * 32, m0 = blockIdx.y * 64;
    int tid = threadIdx.x;
    int wv = tid >> 6, lane = tid & 63, row = lane & 15, kg = lane >> 4;
    const u16* gr = gbf + (size_t)(m0 + wv*16 + row) * PROJ;
    f32x4 acc[2];
    #pragma unroll
    for (int i = 0; i < 2; ++i) acc[i] = (f32x4){0.f,0.f,0.f,0.f};
    for (int ks = 0; ks < 32; ++ks) {
        int kbase = ks*32 + kg*8;
        bf16x8 av  = *(const bf16x8*)(gr + kbase);
        bf16x8 bv0 = *(const bf16x8*)(fwbf + (size_t)(n0      + row)*PROJ + kbase);
        bf16x8 bv1 = *(const bf16x8*)(fwbf + (size_t)(n0 + 16 + row)*PROJ + kbase);
        acc[0] = __builtin_amdgcn_mfma_f32_16x16x32_bf16(av, bv0, acc[0], 0, 0, 0);
        acc[1] = __builtin_amdgcn_mfma_f32_16x16x32_bf16(av, bv1, acc[1], 0, 0, 0);
    }
    int m = m0 + wv*16 + kg*4;
    #pragma unroll
    for (int nf = 0; nf < 2; ++nf) {
        int n = n0 + nf*16 + row;
        float bias = fb[n];
        #pragma unroll
        for (int r = 0; r < 4; ++r)
            h2[(size_t)(m + r)*PROJ + n] = acc[nf][r] + bias + h1[(size_t)(m + r)*PROJ + n];
    }
}

// ---------------- kG3: LayerNorm rows of 1024 ----------------
__global__ __launch_bounds__(256) void kG3(const float* __restrict__ h2, const float* __restrict__ lg,
                                           const float* __restrict__ lb, float* __restrict__ out) {
    int b = blockIdx.x, tid = threadIdx.x;
    float4 v = *(const float4*)&h2[(size_t)b*PROJ + tid*4];
    float s = v.x + v.y + v.z + v.w;
    float q = v.x*v.x + v.y*v.y + v.z*v.z + v.w*v.w;
    __shared__ float ps[4], pq[4], mb[2];
    int wave = tid >> 6, lane = tid & 63;
    #pragma unroll
    for (int d = 32; d >= 1; d >>= 1) { s += __shfl_down(s, d); q += __shfl_down(q, d); }
    if (lane == 0) { ps[wave] = s; pq[wave] = q; }
    __syncthreads();
    if (tid == 0) {
        float S = ps[0]+ps[1]+ps[2]+ps[3], Q = pq[0]+pq[1]+pq[2]+pq[3];
        float mean = S / 1024.f, var = Q / 1024.f - mean*mean;
        mb[0] = mean; mb[1] = rsqrtf(var + 1e-5f);
    }
    __syncthreads();
    float mean = mb[0], inv = mb[1];
    float4 g4 = *(const float4*)&lg[tid*4];
    float4 b4 = *(const float4*)&lb[tid*4];
    float4 o4;
    o4.x = (v.x - mean)*inv*g4.x + b4.x;
    o4.y = (v.y - mean)*inv*g4.y + b4.y;
    o4.z = (v.z - mean)*inv*g4.z + b4.z;
    o4.w = (v.w - mean)*inv*g4.w + b4.w;
    *(float4*)&out[(size_t)b*PROJ + tid*4] = o4;
}

extern "C" void kernel_launch(void* const* d_in, const int* in_sizes, int n_in,
                              void* d_out, int out_size, void* d_ws, size_t ws_size,
                              hipStream_t stream) {
    const float* x       = (const float*)d_in[0];
    const int*   subjects= (const int*)  d_in[1];
    const float* W_subj  = (const float*)d_in[2];
    const float* b_subj  = (const float*)d_in[3];
    const float* conv1_w = (const float*)d_in[4];
    const float* conv1_b = (const float*)d_in[5];
    const float* bn1_g   = (const float*)d_in[6];
    const float* bn1_b   = (const float*)d_in[7];
    const float* conv2_w = (const float*)d_in[8];
    const float* conv2_b = (const float*)d_in[9];
    const float* bn2_g   = (const float*)d_in[10];
    const float* bn2_b   = (const float*)d_in[11];
    const float* proj_w  = (const float*)d_in[12];
    const float* proj_b  = (const float*)d_in[13];
    const float* fc1_w   = (const float*)d_in[14];
    const float* fc1_b   = (const float*)d_in[15];
    const float* fc2_w   = (const float*)d_in[16];
    const float* fc2_b   = (const float*)d_in[17];
    const float* ln_g    = (const float*)d_in[18];
    const float* ln_b    = (const float*)d_in[19];
    float* out = (float*)d_out;

    char* ws = (char*)d_ws;
    float* xeeg  = (float*)ws;                          // 32,256,000 B
    u16*   pooled= (u16*)  (ws + 32256000);             // 118,702,080 B
    float* out2  = (float*)(ws + 150958080);            // 3,768,320 B
    float* z     = (float*)(ws + 154726400);            // 376,832 B
    float* h1    = (float*)(ws + 155103232);            // 2,097,152 B
    float* h2    = (float*)(ws + 157200384);            // 2,097,152 B
    u16*   gbf   = (u16*)  (ws + 159297536);            // 1,048,576 B
    float* stats = (float*)(ws + 160346112);            // 1,280 B (pad 4096)
    u16*   Wbf   = (u16*)  (ws + 160350208);            // 1,310,720 B
    u16*   Wbf2  = (u16*)  (ws + 161660928);            // 242,688 B
    u16*   fwbf  = (u16*)  ws;                          // aliases xeeg (dead after kB)

    kZ  <<<1, 512, 0, stream>>>(stats);
    kXa <<<2560, 256, 0, stream>>>(W_subj, Wbf);
    kXd <<<474, 256, 0, stream>>>(conv2_w, Wbf2);
    kA  <<<512, 256, 0, stream>>>(x, subjects, Wbf, b_subj, xeeg);
    kB  <<<dim3(512, 3), 256, 0, stream>>>(xeeg, conv1_w, conv1_b, (__hip_bfloat16*)pooled, stats);
    kXg <<<4096, 256, 0, stream>>>(fc2_w, fwbf);        // after kB: xeeg dead
    kC  <<<1, 64, 0, stream>>>(stats, bn1_g, bn1_b);
    kD  <<<368, 256, 0, stream>>>(pooled, Wbf2, conv2_b, stats, out2, stats);
    kE2 <<<1, 64, 0, stream>>>(stats, bn2_g, bn2_b);
    kF  <<<512, 256, 0, stream>>>(out2, stats, proj_w, proj_b, z);
    kG1 <<<dim3(16, 8), 256, 0, stream>>>(z, fc1_w, fc1_b, h1, gbf);
    kG2 <<<dim3(32, 8), 256, 0, stream>>>(gbf, fwbf, fc2_b, h1, h2);
    kG3 <<<512, 256, 0, stream>>>(h2, ln_g, ln_b, out);
    (void)in_sizes; (void)n_in; (void)out_size; (void)ws_size;
}

// Round 3
// 290.959 us; speedup vs baseline: 4.1675x; 1.6613x over previous
//
#include <hip/hip_runtime.h>
#include <hip/hip_bf16.h>

#define K2 2520
#define PROJ 1024
#define HID 184
#define N1F (512.f*63.f*46.f)
#define N2F (512.f*46.f)

typedef float f32x4 __attribute__((ext_vector_type(4)));
typedef short bf16x8 __attribute__((ext_vector_type(8)));
typedef unsigned short u16;
typedef unsigned short ushort8 __attribute__((ext_vector_type(8)));

__device__ __forceinline__ u16 f2bf(float f) {   // RNE fp32 -> bf16 bits
    unsigned u = __builtin_bit_cast(unsigned, f);
    return (u16)((u + 0x7FFFu + ((u >> 16) & 1u)) >> 16);
}
__device__ __forceinline__ float bf2f(u16 h) {
    unsigned u = ((unsigned)h) << 16;
    return __builtin_bit_cast(float, u);
}

// ---------------- kZ: zero stats[0..320) ----------------
__global__ void kZ(float* stats) {
    int t = threadIdx.x;
    if (t < 320) stats[t] = 0.f;
}

// ---------------- prep: W_subj -> bf16 [10][256][256], zero-padded ----------------
__global__ void kXa(const float* __restrict__ W, u16* __restrict__ Wbf) {
    int i = blockIdx.x * 256 + threadIdx.x;          // grid 2560
    int sj = i >> 16, s_ = (i >> 8) & 255, t_ = i & 255;
    float v = (s_ < 250 && t_ < 250) ? W[(size_t)sj*62500 + s_*250 + t_] : 0.f;
    Wbf[i] = f2bf(v);
}
// ---------------- prep: conv2_w -> bf16 [48][2528], k = c*40+o ----------------
__global__ void kXd(const float* __restrict__ w2, u16* __restrict__ Wbf2) {
    int i = blockIdx.x * 256 + threadIdx.x;          // grid 474 (=121344/256)
    int n = i / 2528, k = i - n * 2528;
    float v = 0.f;
    if (n < 40 && k < K2) { int c = k / 40, o = k - c * 40; v = w2[n*K2 + o*63 + c]; }
    Wbf2[i] = f2bf(v);
}
// ---------------- prep: fc1_w -> bf16 [1024][192], zero-padded ----------------
__global__ void kXf(const float* __restrict__ fw, u16* __restrict__ fwbf1) {
    int i = blockIdx.x * 256 + threadIdx.x;          // grid 768 (=196608/256)
    int n = i / 192, k = i - n * 192;
    fwbf1[i] = f2bf(k < HID ? fw[n*HID + k] : 0.f);
}
// ---------------- prep: fc2_w -> bf16 [1024][1024] ----------------
__global__ void kXg(const float* __restrict__ fw, u16* __restrict__ fwbf) {
    int i = blockIdx.x * 256 + threadIdx.x;          // grid 4096
    fwbf[i] = f2bf(fw[i]);
}

// ---------------- kAB: fused subject-matmul (MFMA) + conv1+avgpool -> pooled ------------
// grid 512 (b), block 256. Phase1: xeeg tile in regs -> LDS. Phase2: sliding-window conv.
// pooled layout: [b][w][k], k = c*40 + o. Also bn1 partial sums.
#define XS(c,s) xs[(c)*258 + (s)]
__global__ __launch_bounds__(256) void kAB(const float* __restrict__ x,
                                           const int* __restrict__ subj,
                                           const u16* __restrict__ Wbf,
                                           const float* __restrict__ bsub,
                                           const float* __restrict__ w1,
                                           const float* __restrict__ b1,
                                           u16* __restrict__ pooled,
                                           float* __restrict__ stats) {
    __shared__ float xs[64 * 258];      // 66 KB
    __shared__ float effs[40 * 22];
    __shared__ float biasL[256];
    __shared__ float sS[6][40], sQ[6][40];
    int b = blockIdx.x;
    int sj = subj[b];
    int tid = threadIdx.x;

    // phase 0: bias row + effective 21-tap filter
    biasL[tid] = (tid < 250) ? bsub[sj*250 + tid] : 0.f;
    for (int i = tid; i < 840; i += 256) {
        int o = i / 21, j = i - o * 21;
        float e = 0.f;
        #pragma unroll
        for (int k = 0; k < 5; ++k) { int u = j - k; if (u >= 0 && u <= 16) e += w1[o*5 + k]; }
        effs[o*22 + j] = e * (1.f / 17.f);
    }

    // phase 1: MFMA x_eeg tile (rows c, cols s)
    int wv = tid >> 6, lane = tid & 63, row = lane & 15, kg = lane >> 4;
    int c = wv*16 + row;
    const float* xr = x + ((size_t)b*63 + (c < 63 ? c : 62))*250;
    const u16* Wb = Wbf + (size_t)sj*65536;
    f32x4 acc[16];
    #pragma unroll
    for (int i = 0; i < 16; ++i) acc[i] = (f32x4){0.f,0.f,0.f,0.f};

    #pragma unroll
    for (int ks = 0; ks < 8; ++ks) {
        int tb = ks*32 + kg*8;
        float av[8];
        if (ks < 7) {
            #pragma unroll
            for (int j = 0; j < 8; j += 2) { float2 v = *(const float2*)&xr[tb+j]; av[j]=v.x; av[j+1]=v.y; }
        } else {
            #pragma unroll
            for (int j = 0; j < 8; ++j) av[j] = 0.f;
            if (kg < 3) {
                #pragma unroll
                for (int j = 0; j < 8; j += 2) { float2 v = *(const float2*)&xr[tb+j]; av[j]=v.x; av[j+1]=v.y; }
            } else {
                float2 v = *(const float2*)&xr[248]; av[0]=v.x; av[1]=v.y;
            }
        }
        bf16x8 af;
        #pragma unroll
        for (int j = 0; j < 8; ++j) af[j] = (short)f2bf(av[j]);
        #pragma unroll
        for (int nf = 0; nf < 16; ++nf) {
            bf16x8 bv = *(const bf16x8*)(Wb + (size_t)(nf*16 + row)*256 + tb);
            acc[nf] = __builtin_amdgcn_mfma_f32_16x16x32_bf16(af, bv, acc[nf], 0, 0, 0);
        }
    }
    __syncthreads();    // biasL/effs ready; now write tile to LDS
    int cD = wv*16 + kg*4;
    #pragma unroll
    for (int nf = 0; nf < 16; ++nf) {
        int s = nf*16 + row;
        float bias = biasL[s];
        #pragma unroll
        for (int r = 0; r < 4; ++r) XS(cD + r, s) = acc[nf][r] + bias;
    }
    __syncthreads();

    // phase 2: conv+pool, thread = (cg, o), sliding register window over w
    float ssum = 0.f, ssq = 0.f;
    if (tid < 240) {
        int o = tid % 40, cg = tid / 40;
        float eff[21];
        #pragma unroll
        for (int j = 0; j < 21; ++j) eff[j] = effs[o*22 + j];
        float bo = b1[o];
        u16* prow = pooled + (size_t)b * 46 * K2;
        for (int c2 = cg; c2 < 63; c2 += 6) {
            float win[21];
            #pragma unroll
            for (int j = 0; j < 21; ++j) win[j] = XS(c2, j);
            int kidx = c2*40 + o;
            #pragma unroll
            for (int w = 0; w < 46; ++w) {
                float a = bo;
                #pragma unroll
                for (int j = 0; j < 21; ++j) a = fmaf(win[j], eff[j], a);
                prow[(size_t)w*K2 + kidx] = f2bf(a);
                ssum += a; ssq += a*a;
                if (w < 45) {
                    #pragma unroll
                    for (int j2 = 0; j2 < 16; ++j2) win[j2] = win[j2+5];
                    #pragma unroll
                    for (int j2 = 16; j2 < 21; ++j2) win[j2] = XS(c2, 5*w + 5 + j2);
                }
            }
        }
        sS[cg][o] = ssum; sQ[cg][o] = ssq;
    }
    __syncthreads();
    if (tid < 40) {
        float s = 0.f, q = 0.f;
        #pragma unroll
        for (int g = 0; g < 6; ++g) { s += sS[g][tid]; q += sQ[g][tid]; }
        atomicAdd(&stats[tid], s);
        atomicAdd(&stats[40 + tid], q);
    }
}

// ---------------- kC: finalize bn1 -> sc1/sh1 (packed float2) ----------------
__global__ void kC(float* stats, const float* __restrict__ g1, const float* __restrict__ bb1) {
    int t = threadIdx.x;
    if (t < 40) {
        float mean = stats[t] / N1F;
        float var  = stats[40 + t] / N1F - mean * mean;
        float sc   = g1[t] * rsqrtf(var + 1e-5f);
        stats[80 + t]  = sc;
        stats[120 + t] = bb1[t] - mean * sc;
    }
}

// ---------------- kD: out2 = elu(bn1(pooled)) @ w2^T + b2 (MFMA, split-K) + bn2 sums ----
// grid 736 (m-tiles of 32), block 256: waves {rowgrp 0,1} x {khalf 0,1}.
__global__ __launch_bounds__(256) void kD(const u16* __restrict__ pooled,
                                          const u16* __restrict__ Wbf2,
                                          const float* __restrict__ b2,
                                          const float* __restrict__ stats,
                                          float* __restrict__ out2,
                                          float* __restrict__ statw) {
    __shared__ float2 scsh[40];
    __shared__ float mrg[2][64][12];
    __shared__ float redS[2][48], redQ[2][48];
    int tid = threadIdx.x;
    if (tid < 40) scsh[tid] = make_float2(stats[80 + tid], stats[120 + tid]);
    __syncthreads();
    int wv = tid >> 6, lane = tid & 63, row = lane & 15, kg = lane >> 4;
    int rowgrp = wv >> 1, khalf = wv & 1;
    int mbase = blockIdx.x*32 + rowgrp*16;
    const u16* pr = pooled + (size_t)(mbase + row) * K2;
    f32x4 acc[3];
    #pragma unroll
    for (int i = 0; i < 3; ++i) acc[i] = (f32x4){0.f,0.f,0.f,0.f};

    int ksBeg = khalf ? 39 : 0, ksEnd = khalf ? 79 : 39;
    for (int ks = ksBeg; ks < ksEnd; ++ks) {
        int kbase = ks*32 + kg*8;
        ushort8 cur = *(const ushort8*)&pr[kbase];
        bf16x8 bv0 = *(const bf16x8*)(Wbf2 + (size_t)(row     )*2528 + kbase);
        bf16x8 bv1 = *(const bf16x8*)(Wbf2 + (size_t)(16 + row)*2528 + kbase);
        bf16x8 bv2 = *(const bf16x8*)(Wbf2 + (size_t)(32 + row)*2528 + kbase);
        bf16x8 af;
        bool valid = (ks < 78) | (kg < 3);
        if (valid) {
            #pragma unroll
            for (int j = 0; j < 8; ++j) {
                int k = kbase + j;
                int u = (k * 1639) >> 16;            // k/40 for k<2731
                int o = k - u*40;
                float2 ss = scsh[o];
                float a = fmaf(bf2f(cur[j]), ss.x, ss.y);
                float e = a > 0.f ? a : __expf(a) - 1.f;
                af[j] = (short)f2bf(e);
            }
        } else {
            #pragma unroll
            for (int j = 0; j < 8; ++j) af[j] = 0;
        }
        acc[0] = __builtin_amdgcn_mfma_f32_16x16x32_bf16(af, bv0, acc[0], 0, 0, 0);
        acc[1] = __builtin_amdgcn_mfma_f32_16x16x32_bf16(af, bv1, acc[1], 0, 0, 0);
        acc[2] = __builtin_amdgcn_mfma_f32_16x16x32_bf16(af, bv2, acc[2], 0, 0, 0);
    }

    if (khalf) {
        #pragma unroll
        for (int nf = 0; nf < 3; ++nf)
            #pragma unroll
            for (int r = 0; r < 4; ++r) mrg[rowgrp][lane][nf*4 + r] = acc[nf][r];
    }
    __syncthreads();
    if (!khalf) {
        float sN[3] = {0.f,0.f,0.f}, qN[3] = {0.f,0.f,0.f};
        #pragma unroll
        for (int nf = 0; nf < 3; ++nf) {
            int n = nf*16 + row;
            #pragma unroll
            for (int r = 0; r < 4; ++r) acc[nf][r] += mrg[rowgrp][lane][nf*4 + r];
            if (n < 40) {
                float bias = b2[n];
                #pragma unroll
                for (int r = 0; r < 4; ++r) {
                    float v = acc[nf][r] + bias;
                    out2[(size_t)(mbase + kg*4 + r)*40 + n] = v;
                    sN[nf] += v; qN[nf] += v*v;
                }
            }
        }
        #pragma unroll
        for (int nf = 0; nf < 3; ++nf) {
            float s = sN[nf], q = qN[nf];
            s += __shfl_xor(s, 16); q += __shfl_xor(q, 16);
            s += __shfl_xor(s, 32); q += __shfl_xor(q, 32);
            if (kg == 0) { redS[rowgrp][nf*16 + row] = s; redQ[rowgrp][nf*16 + row] = q; }
        }
    }
    __syncthreads();
    if (tid < 40) {
        atomicAdd(&statw[160 + tid], redS[0][tid] + redS[1][tid]);
        atomicAdd(&statw[200 + tid], redQ[0][tid] + redQ[1][tid]);
    }
}

// ---------------- kE2: finalize bn2 -> sc2/sh2 ----------------
__global__ void kE2(float* stats, const float* __restrict__ g2, const float* __restrict__ bb2) {
    int t = threadIdx.x;
    if (t < 40) {
        float mean = stats[160 + t] / N2F;
        float var  = stats[200 + t] / N2F - mean * mean;
        float s    = g2[t] * rsqrtf(var + 1e-5f);
        stats[240 + t] = s;
        stats[280 + t] = bb2[t] - mean * s;
    }
}

// ---------------- kF: bn2+elu+proj -> z bf16 [512][192] ----------------
__global__ void kF(const float* __restrict__ out2, const float* __restrict__ stats,
                   const float* __restrict__ pw, const float* __restrict__ pb,
                   u16* __restrict__ zbf) {
    int b = blockIdx.x, t = threadIdx.x;
    __shared__ float sc[40], sh[40], pws[160];
    __shared__ float o2[1840];
    if (t < 40) { sc[t] = stats[240 + t]; sh[t] = stats[280 + t]; }
    if (t < 160) pws[t] = pw[t];
    for (int i = t; i < 1840; i += 256) o2[i] = out2[(size_t)b*1840 + i];
    __syncthreads();
    if (t < 192) {
        float accv = 0.f;
        if (t < HID) {
            int w = t >> 2, e = t & 3;
            accv = pb[e];
            for (int o = 0; o < 40; ++o) {
                float a = o2[w*40 + o];
                float act = a * sc[o] + sh[o];
                act = act > 0.f ? act : __expf(act) - 1.f;
                accv = fmaf(act, pws[e*40 + o], accv);
            }
        }
        zbf[(size_t)b*192 + t] = f2bf(accv);
    }
}

// ---------------- kG1: h1 = z @ fc1_w^T + b (MFMA); g = gelu(h1) bf16 ----------------
// grid (16 nblk, 32 mblk): m-tile 16, n-tile 64 (wave = one 16-n frag).
__global__ __launch_bounds__(256) void kG1(const u16* __restrict__ zbf, const u16* __restrict__ fwbf1,
                                           const float* __restrict__ fb,
                                           float* __restrict__ h1, u16* __restrict__ gbf) {
    int n0 = blockIdx.x * 64, m0 = blockIdx.y * 16;
    int tid = threadIdx.x, wv = tid >> 6, lane = tid & 63, row = lane & 15, kg = lane >> 4;
    const u16* zr = zbf + (size_t)(m0 + row) * 192;
    const u16* wr = fwbf1 + (size_t)(n0 + wv*16 + row) * 192;
    f32x4 acc = (f32x4){0.f,0.f,0.f,0.f};
    #pragma unroll
    for (int ks = 0; ks < 6; ++ks) {
        bf16x8 av = *(const bf16x8*)(zr + ks*32 + kg*8);
        bf16x8 bv = *(const bf16x8*)(wr + ks*32 + kg*8);
        acc = __builtin_amdgcn_mfma_f32_16x16x32_bf16(av, bv, acc, 0, 0, 0);
    }
    int n = n0 + wv*16 + row;
    float bias = fb[n];
    #pragma unroll
    for (int r = 0; r < 4; ++r) {
        int m = m0 + kg*4 + r;
        float v = acc[r] + bias;
        h1[(size_t)m*PROJ + n] = v;
        float ge = 0.5f * v * (1.f + erff(v * 0.70710678118f));
        gbf[(size_t)m*PROJ + n] = f2bf(ge);
    }
}

// ---------------- kG2: h2 = h1 + g @ fc2_w^T + b (MFMA) ----------------
__global__ __launch_bounds__(256) void kG2(const u16* __restrict__ gbf, const u16* __restrict__ fwbf,
                                           const float* __restrict__ fb, const float* __restrict__ h1,
                                           float* __restrict__ h2) {
    int n0 = blockIdx.x * 32, m0 = blockIdx.y * 64;
    int tid = threadIdx.x;
    int wv = tid >> 6, lane = tid & 63, row = lane & 15, kg = lane >> 4;
    const u16* gr = gbf + (size_t)(m0 + wv*16 + row) * PROJ;
    f32x4 acc[2];
    #pragma unroll
    for (int i = 0; i < 2; ++i) acc[i] = (f32x4){0.f,0.f,0.f,0.f};
    for (int ks = 0; ks < 32; ++ks) {
        int kbase = ks*32 + kg*8;
        bf16x8 av  = *(const bf16x8*)(gr + kbase);
        bf16x8 bv0 = *(const bf16x8*)(fwbf + (size_t)(n0      + row)*PROJ + kbase);
        bf16x8 bv1 = *(const bf16x8*)(fwbf + (size_t)(n0 + 16 + row)*PROJ + kbase);
        acc[0] = __builtin_amdgcn_mfma_f32_16x16x32_bf16(av, bv0, acc[0], 0, 0, 0);
        acc[1] = __builtin_amdgcn_mfma_f32_16x16x32_bf16(av, bv1, acc[1], 0, 0, 0);
    }
    int m = m0 + wv*16 + kg*4;
    #pragma unroll
    for (int nf = 0; nf < 2; ++nf) {
        int n = n0 + nf*16 + row;
        float bias = fb[n];
        #pragma unroll
        for (int r = 0; r < 4; ++r)
            h2[(size_t)(m + r)*PROJ + n] = acc[nf][r] + bias + h1[(size_t)(m + r)*PROJ + n];
    }
}

// ---------------- kG3: LayerNorm rows of 1024 ----------------
__global__ __launch_bounds__(256) void kG3(const float* __restrict__ h2, const float* __restrict__ lg,
                                           const float* __restrict__ lb, float* __restrict__ out) {
    int b = blockIdx.x, tid = threadIdx.x;
    float4 v = *(const float4*)&h2[(size_t)b*PROJ + tid*4];
    float s = v.x + v.y + v.z + v.w;
    float q = v.x*v.x + v.y*v.y + v.z*v.z + v.w*v.w;
    __shared__ float ps[4], pq[4], mb[2];
    int wave = tid >> 6, lane = tid & 63;
    #pragma unroll
    for (int d = 32; d >= 1; d >>= 1) { s += __shfl_down(s, d); q += __shfl_down(q, d); }
    if (lane == 0) { ps[wave] = s; pq[wave] = q; }
    __syncthreads();
    if (tid == 0) {
        float S = ps[0]+ps[1]+ps[2]+ps[3], Q = pq[0]+pq[1]+pq[2]+pq[3];
        float mean = S / 1024.f, var = Q / 1024.f - mean*mean;
        mb[0] = mean; mb[1] = rsqrtf(var + 1e-5f);
    }
    __syncthreads();
    float mean = mb[0], inv = mb[1];
    float4 g4 = *(const float4*)&lg[tid*4];
    float4 b4 = *(const float4*)&lb[tid*4];
    float4 o4;
    o4.x = (v.x - mean)*inv*g4.x + b4.x;
    o4.y = (v.y - mean)*inv*g4.y + b4.y;
    o4.z = (v.z - mean)*inv*g4.z + b4.z;
    o4.w = (v.w - mean)*inv*g4.w + b4.w;
    *(float4*)&out[(size_t)b*PROJ + tid*4] = o4;
}

extern "C" void kernel_launch(void* const* d_in, const int* in_sizes, int n_in,
                              void* d_out, int out_size, void* d_ws, size_t ws_size,
                              hipStream_t stream) {
    const float* x       = (const float*)d_in[0];
    const int*   subjects= (const int*)  d_in[1];
    const float* W_subj  = (const float*)d_in[2];
    const float* b_subj  = (const float*)d_in[3];
    const float* conv1_w = (const float*)d_in[4];
    const float* conv1_b = (const float*)d_in[5];
    const float* bn1_g   = (const float*)d_in[6];
    const float* bn1_b   = (const float*)d_in[7];
    const float* conv2_w = (const float*)d_in[8];
    const float* conv2_b = (const float*)d_in[9];
    const float* bn2_g   = (const float*)d_in[10];
    const float* bn2_b   = (const float*)d_in[11];
    const float* proj_w  = (const float*)d_in[12];
    const float* proj_b  = (const float*)d_in[13];
    const float* fc1_w   = (const float*)d_in[14];
    const float* fc1_b   = (const float*)d_in[15];
    const float* fc2_w   = (const float*)d_in[16];
    const float* fc2_b   = (const float*)d_in[17];
    const float* ln_g    = (const float*)d_in[18];
    const float* ln_b    = (const float*)d_in[19];
    float* out = (float*)d_out;

    char* ws = (char*)d_ws;
    u16*   pooled = (u16*)  ws;                      // 118,702,080 B (+64 pad)
    float* out2   = (float*)(ws + 118702144);        // 3,768,320 B
    u16*   zbf    = (u16*)  (ws + 122470464);        // 196,608 B
    float* h1     = (float*)(ws + 122667072);        // 2,097,152 B
    float* h2     = (float*)(ws + 124764224);        // 2,097,152 B
    u16*   gbf    = (u16*)  (ws + 126861376);        // 1,048,576 B
    float* stats  = (float*)(ws + 127909952);        // 1,280 B (pad 4096)
    u16*   Wbf    = (u16*)  (ws + 127914048);        // 1,310,720 B
    u16*   Wbf2   = (u16*)  (ws + 129224768);        // 242,688 B
    u16*   fwbf2  = (u16*)  (ws + 129467456);        // 2,097,152 B
    u16*   fwbf1  = (u16*)  (ws + 131564608);        // 393,216 B

    kZ  <<<1, 512, 0, stream>>>(stats);
    kXa <<<2560, 256, 0, stream>>>(W_subj, Wbf);
    kXd <<<474, 256, 0, stream>>>(conv2_w, Wbf2);
    kXf <<<768, 256, 0, stream>>>(fc1_w, fwbf1);
    kXg <<<4096, 256, 0, stream>>>(fc2_w, fwbf2);
    kAB <<<512, 256, 0, stream>>>(x, subjects, Wbf, b_subj, conv1_w, conv1_b, pooled, stats);
    kC  <<<1, 64, 0, stream>>>(stats, bn1_g, bn1_b);
    kD  <<<736, 256, 0, stream>>>(pooled, Wbf2, conv2_b, stats, out2, stats);
    kE2 <<<1, 64, 0, stream>>>(stats, bn2_g, bn2_b);
    kF  <<<512, 256, 0, stream>>>(out2, stats, proj_w, proj_b, zbf);
    kG1 <<<dim3(16, 32), 256, 0, stream>>>(zbf, fwbf1, fc1_b, h1, gbf);
    kG2 <<<dim3(32, 8), 256, 0, stream>>>(gbf, fwbf2, fc2_b, h1, h2);
    kG3 <<<512, 256, 0, stream>>>(h2, ln_g, ln_b, out);
    (void)in_sizes; (void)n_in; (void)out_size; (void)ws_size;
}